// Round 8
// baseline (158.901 us; speedup 1.0000x reference)
//
#include <hip/hip_runtime.h>
#include <cstdint>
#include <cstddef>

// ---------------------------------------------------------------------------
// MultiHeadAttention (B=2, S=2048, DIM=1024, H=16, HD=64), causal + RoPE.
// R8: GEMMs get the attn-proven 2-deep staging pipeline: triple-buffered LDS,
// stage(t+2) at iter top, counted vmcnt(4) at iter bottom (T4). Everything
// else identical to R7 (passing).
// ---------------------------------------------------------------------------

typedef __bf16 bf16_t;
typedef __bf16 bf16x8 __attribute__((ext_vector_type(8)));
typedef __bf16 bf16x4 __attribute__((ext_vector_type(4)));
typedef float  f32x4  __attribute__((ext_vector_type(4)));

#define DEVFN __device__ __forceinline__

static constexpr int Bn  = 2;
static constexpr int S   = 2048;
static constexpr int DIM = 1024;
static constexpr int NH  = 16;
static constexpr int HD  = 64;
static constexpr int Mrows = Bn * S;        // 4096

DEVFN f32x4 mfma16(bf16x8 a, bf16x8 b, f32x4 c) {
  return __builtin_amdgcn_mfma_f32_16x16x32_bf16(a, b, c, 0, 0, 0);
}

DEVFN void gl_lds16(const bf16_t* g, bf16_t* l) {
  __builtin_amdgcn_global_load_lds(
      (const __attribute__((address_space(1))) unsigned*)g,
      (__attribute__((address_space(3))) unsigned*)l, 16, 0, 0);
}

// ---------------------------------------------------------------------------
// One launch: all fp32->bf16 converts + rope table.
__global__ __launch_bounds__(256) void k_prep(
    const float* __restrict__ x, const float* __restrict__ wq,
    const float* __restrict__ wk, const float* __restrict__ wv,
    const float* __restrict__ wo, bf16_t* __restrict__ xb,
    bf16_t* __restrict__ wqb, bf16_t* __restrict__ wkb,
    bf16_t* __restrict__ wvb, bf16_t* __restrict__ wob,
    float2* __restrict__ tab) {
  const int bid = blockIdx.x;
  if (bid < 8192) {
    const float* src;
    bf16_t* dst;
    size_t base;
    if (bid < 4096) {
      src = x; dst = xb; base = (size_t)bid << 10;
    } else {
      int wsel = (bid - 4096) >> 10;
      src = wsel == 0 ? wq : wsel == 1 ? wk : wsel == 2 ? wv : wo;
      dst = wsel == 0 ? wqb : wsel == 1 ? wkb : wsel == 2 ? wvb : wob;
      base = (size_t)((bid - 4096) & 1023) << 10;
    }
    size_t i = base + (size_t)threadIdx.x * 4;
    float4 v = *(const float4*)(src + i);
    bf16x4 o = { (bf16_t)v.x, (bf16_t)v.y, (bf16_t)v.z, (bf16_t)v.w };
    *(bf16x4*)(dst + i) = o;
  } else {
    int i = (bid - 8192) * 256 + threadIdx.x;  // < S*32
    int s = i >> 5, d = i & 31;
    float th = (float)s * expf((float)d * -0.2878231366f);  // ln(10000)/32
    tab[i] = make_float2(cosf(th), sinf(th));
  }
}

// ---------------------------------------------------------------------------
// Shared GEMM staging: 128x128 tile, BK=32; per call each thread issues
// 2 A-loads + 2 B-loads (16B each) into the given LDS buffers.
DEVFN void stage_ab(const bf16_t* __restrict__ A, const bf16_t* __restrict__ Bw,
                    bf16_t* Al, bf16_t* Bl, int m0, int n0, int k0, int t,
                    int w) {
#pragma unroll
  for (int ld = 0; ld < 2; ++ld) {
    int c = t + ld * 256;
    int row = c >> 2, j = (c & 3) << 3;
    bf16_t* dstA = Al + (size_t)(w * 64 + ld * 256) * 8;
    bf16_t* dstB = Bl + (size_t)(w * 64 + ld * 256) * 8;
    gl_lds16(A + (size_t)(m0 + row) * DIM + k0 + j, dstA);
    gl_lds16(Bw + (size_t)(n0 + row) * DIM + k0 + j, dstB);
  }
}

// ---------------------------------------------------------------------------
// Fused QKV NT GEMM, single dispatch: M=4096, N=3072 (wq|wk|wv contiguous),
// K=1024. 768 blocks, XCD rectangle swizzle (8m x 12n per XCD). Triple-
// buffered LDS, 2-deep staging: stage(t+2) at iter top, vmcnt(4) at bottom.
// Epilogue per z: Q/K rope (shfl pair), V transposed into VT.
__global__ __launch_bounds__(256) void k_gemm_qkv(
    const bf16_t* __restrict__ A, const bf16_t* __restrict__ Wall,
    const float* __restrict__ c0, const float* __restrict__ c1,
    const float* __restrict__ c2, bf16_t* __restrict__ Oq,
    bf16_t* __restrict__ Ok, bf16_t* __restrict__ VTo,
    const float2* __restrict__ tab) {
  __shared__ __align__(16) bf16_t Al[3][128 * 32];
  __shared__ __align__(16) bf16_t Bl[3][128 * 32];
  const int t = threadIdx.x, w = t >> 6, l = t & 63;
  const int lr = l & 15, lc = l >> 4;
  // bijective XCD rectangle swizzle: xcd = lid&7 owns 8 m-tiles x 12 n-tiles
  const int lid = blockIdx.x;
  const int xcd = lid & 7, s = lid >> 3;          // s in [0,96)
  const int my = ((xcd >> 1) << 3) + (s & 7);     // [0,32)
  const int nx = (xcd & 1) * 12 + (s >> 3);       // [0,24)
  const int m0 = my * 128, n0g = nx * 128;
  const int z = n0g >> 10, n0l = n0g & 1023;
  const int wr = w >> 1, wc = w & 1;
  f32x4 acc[4][4] = {};

  // prologue: stage tiles 0 and 1, wait tile 0
  stage_ab(A, Wall, Al[0], Bl[0], m0, n0g, 0, t, w);
  stage_ab(A, Wall, Al[1], Bl[1], m0, n0g, 32, t, w);
  asm volatile("s_waitcnt vmcnt(4)" ::: "memory");
  __builtin_amdgcn_s_barrier();
  __builtin_amdgcn_sched_barrier(0);

  int bc = 0, bn = 1, bs = 2;  // cur, next, stage-target (= cur+2 mod 3)
  for (int k0 = 0; k0 < DIM; k0 += 32) {
    if (k0 + 64 < DIM)
      stage_ab(A, Wall, Al[bs], Bl[bs], m0, n0g, k0 + 64, t, w);
    bf16x8 af[4], bfr[4];
#pragma unroll
    for (int mi = 0; mi < 4; ++mi)
      af[mi] =
          *(const bf16x8*)(Al[bc] + (wr * 64 + mi * 16 + lr) * 32 + lc * 8);
#pragma unroll
    for (int ni = 0; ni < 4; ++ni)
      bfr[ni] =
          *(const bf16x8*)(Bl[bc] + (wc * 64 + ni * 16 + lr) * 32 + lc * 8);
    __builtin_amdgcn_s_setprio(1);
#pragma unroll
    for (int mi = 0; mi < 4; ++mi)
#pragma unroll
      for (int ni = 0; ni < 4; ++ni)
        acc[mi][ni] = mfma16(af[mi], bfr[ni], acc[mi][ni]);
    __builtin_amdgcn_s_setprio(0);
    if (k0 + 64 < DIM) {
      asm volatile("s_waitcnt vmcnt(4)" ::: "memory");  // stage(t+1) landed
      __builtin_amdgcn_s_barrier();
      __builtin_amdgcn_sched_barrier(0);
    } else if (k0 + 32 < DIM) {
      asm volatile("s_waitcnt vmcnt(0)" ::: "memory");
      __builtin_amdgcn_s_barrier();
      __builtin_amdgcn_sched_barrier(0);
    }
    int tmp = bc; bc = bn; bn = bs; bs = tmp;
  }

  if (z == 2) {
    // V: bias + transposed store VT[bh][d][s], 4 consecutive s per bf16x4
    const int h = (n0l >> 6) + wc;
    const float* bias = c2;
#pragma unroll
    for (int ni = 0; ni < 4; ++ni) {
      const int d = ni * 16 + lr;
      const float bv = bias[n0l + wc * 64 + ni * 16 + lr];
#pragma unroll
      for (int mi = 0; mi < 4; ++mi) {
        int rowb = m0 + wr * 64 + mi * 16 + lc * 4;
        int bb = rowb >> 11, ss = rowb & (S - 1);
        bf16x4 pb = { (bf16_t)(acc[mi][ni][0] + bv),
                      (bf16_t)(acc[mi][ni][1] + bv),
                      (bf16_t)(acc[mi][ni][2] + bv),
                      (bf16_t)(acc[mi][ni][3] + bv) };
        *(bf16x4*)(VTo + ((size_t)(bb * NH + h) * HD + d) * S + ss) = pb;
      }
    }
  } else {
    // Q/K: bias + rope. Pair partner lives in adjacent lr lane.
    bf16_t* Ov = z == 0 ? Oq : Ok;
    const float* bias = z == 0 ? c0 : c1;
    const float scale = z == 0 ? 0.125f : 1.0f;
#pragma unroll
    for (int ni = 0; ni < 4; ++ni) {
      const int col = n0l + wc * 64 + ni * 16 + lr;
      const float bv = bias[col];
      const int p0 = ni * 8 + (lr >> 1);
#pragma unroll
      for (int mi = 0; mi < 4; ++mi) {
#pragma unroll
        for (int r = 0; r < 4; ++r) {
          int row = m0 + wr * 64 + mi * 16 + lc * 4 + r;
          float v = acc[mi][ni][r] + bv;
          float pt = __shfl_xor(v, 1);
          float2 cs = tab[(row & (S - 1)) * 32 + p0];
          float out = (lr & 1) ? (pt * cs.y + v * cs.x)
                               : (v * cs.x - pt * cs.y);
          Ov[(size_t)row * DIM + col] = (bf16_t)(out * scale);
        }
      }
    }
  }
}

// ---------------------------------------------------------------------------
// Out projection: M=4096, N=1024, K=1024. 256 blocks, XCD rectangle swizzle.
// Same 3-buffer 2-deep pipeline.
__global__ __launch_bounds__(256) void k_gemm_out(
    const bf16_t* __restrict__ A, const bf16_t* __restrict__ Bw,
    const float* __restrict__ bias, float* __restrict__ Ov) {
  __shared__ __align__(16) bf16_t Al[3][128 * 32];
  __shared__ __align__(16) bf16_t Bl[3][128 * 32];
  const int t = threadIdx.x, w = t >> 6, l = t & 63;
  const int lr = l & 15, lc = l >> 4;
  const int lid = blockIdx.x;
  const int xcd = lid & 7, s = lid >> 3;          // s in [0,32)
  const int my = ((xcd >> 1) << 3) + (s & 7);     // [0,32)
  const int nx = (xcd & 1) * 4 + (s >> 3);        // [0,8)
  const int m0 = my * 128, n0 = nx * 128;
  const int wr = w >> 1, wc = w & 1;
  f32x4 acc[4][4] = {};

  stage_ab(A, Bw, Al[0], Bl[0], m0, n0, 0, t, w);
  stage_ab(A, Bw, Al[1], Bl[1], m0, n0, 32, t, w);
  asm volatile("s_waitcnt vmcnt(4)" ::: "memory");
  __builtin_amdgcn_s_barrier();
  __builtin_amdgcn_sched_barrier(0);

  int bc = 0, bn = 1, bs = 2;
  for (int k0 = 0; k0 < DIM; k0 += 32) {
    if (k0 + 64 < DIM)
      stage_ab(A, Bw, Al[bs], Bl[bs], m0, n0, k0 + 64, t, w);
    bf16x8 af[4], bfr[4];
#pragma unroll
    for (int mi = 0; mi < 4; ++mi)
      af[mi] =
          *(const bf16x8*)(Al[bc] + (wr * 64 + mi * 16 + lr) * 32 + lc * 8);
#pragma unroll
    for (int ni = 0; ni < 4; ++ni)
      bfr[ni] =
          *(const bf16x8*)(Bl[bc] + (wc * 64 + ni * 16 + lr) * 32 + lc * 8);
    __builtin_amdgcn_s_setprio(1);
#pragma unroll
    for (int mi = 0; mi < 4; ++mi)
#pragma unroll
      for (int ni = 0; ni < 4; ++ni)
        acc[mi][ni] = mfma16(af[mi], bfr[ni], acc[mi][ni]);
    __builtin_amdgcn_s_setprio(0);
    if (k0 + 64 < DIM) {
      asm volatile("s_waitcnt vmcnt(4)" ::: "memory");
      __builtin_amdgcn_s_barrier();
      __builtin_amdgcn_sched_barrier(0);
    } else if (k0 + 32 < DIM) {
      asm volatile("s_waitcnt vmcnt(0)" ::: "memory");
      __builtin_amdgcn_s_barrier();
      __builtin_amdgcn_sched_barrier(0);
    }
    int tmp = bc; bc = bn; bn = bs; bs = tmp;
  }

#pragma unroll
  for (int ni = 0; ni < 4; ++ni) {
    int col = n0 + wc * 64 + ni * 16 + lr;
    float bv = bias[col];
#pragma unroll
    for (int mi = 0; mi < 4; ++mi)
#pragma unroll
      for (int r = 0; r < 4; ++r) {
        int row = m0 + wr * 64 + mi * 16 + lc * 4 + r;
        Ov[(size_t)row * DIM + col] = acc[mi][ni][r] + bv;
      }
  }
}

// ---------------------------------------------------------------------------
// Causal flash attention (R5 structure, unchanged — passing).
DEVFN void stage_kv(const bf16_t* __restrict__ Kc,
                    const bf16_t* __restrict__ VT, bf16_t* Kb, bf16_t* Vb,
                    int b, int bh, int h, int k0, int tid, int w) {
#pragma unroll
  for (int ld = 0; ld < 2; ++ld) {
    int c = tid + ld * 256;
    int row = c >> 3;
    int j = ((c & 7) ^ (row & 7)) << 3;  // pre-swizzled source chunk
    bf16_t* dstK = Kb + (size_t)(w * 64 + ld * 256) * 8;
    bf16_t* dstV = Vb + (size_t)(w * 64 + ld * 256) * 8;
    gl_lds16(Kc + (size_t)(b * S + k0 + row) * DIM + h * HD + j, dstK);
    gl_lds16(VT + ((size_t)bh * HD + row) * S + k0 + j, dstV);
  }
}

__global__ __launch_bounds__(256) void k_attn(const bf16_t* __restrict__ Q,
                                              const bf16_t* __restrict__ Kc,
                                              const bf16_t* __restrict__ VT,
                                              bf16_t* __restrict__ O) {
  __shared__ __align__(16) bf16_t Kl[2][64 * 64];
  __shared__ __align__(16) bf16_t Vl[3][64 * 64];
  __shared__ __align__(16) bf16_t Pl[4][16 * 64];
  const int tid = threadIdx.x, w = tid >> 6, l = tid & 63;
  const int lr = l & 15, lc = l >> 4;
  const int lid = blockIdx.x + (blockIdx.y << 4);
  const int xcd = lid & 7, slot = lid >> 3;
  const int bh = xcd * 4 + (slot >> 4);
  const int a = slot & 15;
  const int b = bh >> 4, h = bh & 15;
  char* Pw = (char*)&Pl[w][0];

#pragma unroll 1
  for (int pi = 0; pi < 2; ++pi) {
    const int tile = (pi == 0) ? a : 31 - a;
    const int q0 = tile * 64;
    const int nt = tile + 1;

    bf16x8 qf[2];
    {
      const bf16_t* qp =
          Q + (size_t)(b * S + q0 + w * 16 + lr) * DIM + h * HD + lc * 8;
      qf[0] = *(const bf16x8*)qp;
      qf[1] = *(const bf16x8*)(qp + 32);
    }
    f32x4 o[4] = {};
    f32x4 sA[4], sB[4];
    float m_run = -INFINITY;
    float rowsum = 0.f;

    auto qkt = [&](f32x4(&sd)[4], const bf16_t* Kb) {
#pragma unroll
      for (int ni = 0; ni < 4; ++ni) sd[ni] = f32x4{0.f, 0.f, 0.f, 0.f};
      __builtin_amdgcn_s_setprio(1);
#pragma unroll
      for (int ks = 0; ks < 2; ++ks)
#pragma unroll
        for (int ni = 0; ni < 4; ++ni) {
          int row = ni * 16 + lr;
          int off = (ks * 64 + lc * 16) ^ ((row & 7) << 4);
          bf16x8 kf = *(const bf16x8*)((const char*)Kb + row * 128 + off);
          sd[ni] = mfma16(kf, qf[ks], sd[ni]);
        }
      __builtin_amdgcn_s_setprio(0);
    };

    stage_kv(Kc, VT, &Kl[0][0], &Vl[0][0], b, bh, h, 0, tid, w);
    if (nt > 1) {
      stage_kv(Kc, VT, &Kl[1][0], &Vl[1][0], b, bh, h, 64, tid, w);
      asm volatile("s_waitcnt vmcnt(4)" ::: "memory");
    } else {
      asm volatile("s_waitcnt vmcnt(0)" ::: "memory");
    }
    __builtin_amdgcn_s_barrier();
    __builtin_amdgcn_sched_barrier(0);
    qkt(sA, &Kl[0][0]);
    __builtin_amdgcn_s_barrier();

    auto body = [&](f32x4(&scur)[4], f32x4(&snxt)[4], int t) {
      if (t + 2 < nt)
        stage_kv(Kc, VT, &Kl[(t + 2) & 1][0], &Vl[(t + 2) % 3][0], b, bh, h,
                 (t + 2) * 64, tid, w);
      if (t + 1 < nt) {
        if (t + 2 < nt)
          asm volatile("s_waitcnt vmcnt(4)" ::: "memory");
        else
          asm volatile("s_waitcnt vmcnt(0)" ::: "memory");
        __builtin_amdgcn_s_barrier();
        __builtin_amdgcn_sched_barrier(0);
        qkt(snxt, &Kl[(t + 1) & 1][0]);
      }

      if (t == nt - 1) {
        const int qloc = w * 16 + lr;
#pragma unroll
        for (int ni = 0; ni < 4; ++ni)
#pragma unroll
          for (int r = 0; r < 4; ++r)
            if (ni * 16 + lc * 4 + r > qloc) scur[ni][r] = -INFINITY;
      }

      float pm = scur[0][0];
#pragma unroll
      for (int ni = 0; ni < 4; ++ni)
#pragma unroll
        for (int r = 0; r < 4; ++r) pm = fmaxf(pm, scur[ni][r]);
      pm = fmaxf(pm, __shfl_xor(pm, 16));
      pm = fmaxf(pm, __shfl_xor(pm, 32));

      if (__ballot(pm > m_run + 8.f)) {
        float mn = fmaxf(m_run, pm);
        float alpha = __expf(m_run - mn);
        m_run = mn;
        rowsum *= alpha;
#pragma unroll
        for (int r = 0; r < 4; ++r) {
          float aq = __shfl(alpha, lc * 4 + r);
#pragma unroll
          for (int ni = 0; ni < 4; ++ni) o[ni][r] *= aq;
        }
      }

      float rs = 0.f;
#pragma unroll
      for (int ni = 0; ni < 4; ++ni) {
        float p0 = __expf(scur[ni][0] - m_run);
        float p1 = __expf(scur[ni][1] - m_run);
        float p2 = __expf(scur[ni][2] - m_run);
        float p3 = __expf(scur[ni][3] - m_run);
        rs += (p0 + p1) + (p2 + p3);
        bf16x4 pb = { (bf16_t)p0, (bf16_t)p1, (bf16_t)p2, (bf16_t)p3 };
        *(bf16x4*)(Pw + (lr * 128 + ((ni * 32 + lc * 8) ^ ((lr & 7) << 4)))) =
            pb;
      }
      rs += __shfl_xor(rs, 16);
      rs += __shfl_xor(rs, 32);
      rowsum += rs;

      const bf16_t* Vb = &Vl[t % 3][0];
      __builtin_amdgcn_s_setprio(1);
#pragma unroll
      for (int ks = 0; ks < 2; ++ks) {
        int off = ks * 64 + lc * 16;
        bf16x8 pa = *(const bf16x8*)(Pw + lr * 128 + (off ^ ((lr & 7) << 4)));
#pragma unroll
        for (int ni = 0; ni < 4; ++ni) {
          int vrow = ni * 16 + lr;
          bf16x8 vb = *(const bf16x8*)((const char*)Vb + vrow * 128 +
                                       (off ^ ((vrow & 7) << 4)));
          o[ni] = mfma16(pa, vb, o[ni]);
        }
      }
      __builtin_amdgcn_s_setprio(0);

      __builtin_amdgcn_s_barrier();
    };

#pragma unroll 1
    for (int t = 0; t < nt; ++t) {
      if (t & 1)
        body(sB, sA, t);
      else
        body(sA, sB, t);
    }

    float inv[4];
#pragma unroll
    for (int r = 0; r < 4; ++r) inv[r] = 1.0f / __shfl(rowsum, lc * 4 + r);
#pragma unroll
    for (int ni = 0; ni < 4; ++ni)
#pragma unroll
      for (int r = 0; r < 4; ++r) {
        int qr = q0 + w * 16 + lc * 4 + r;
        float v = o[ni][r] * inv[r];
        O[(size_t)(b * S + qr) * DIM + h * HD + ni * 16 + lr] = (bf16_t)v;
      }
  }
}

// ---------------------------------------------------------------------------
extern "C" void kernel_launch(void* const* d_in, const int* in_sizes, int n_in,
                              void* d_out, int out_size, void* d_ws,
                              size_t ws_size, hipStream_t stream) {
  const float* x  = (const float*)d_in[0];
  const float* wq = (const float*)d_in[1];
  const float* bq = (const float*)d_in[2];
  const float* wk = (const float*)d_in[3];
  const float* bk = (const float*)d_in[4];
  const float* wv = (const float*)d_in[5];
  const float* bv = (const float*)d_in[6];
  const float* wo = (const float*)d_in[7];
  const float* bo = (const float*)d_in[8];

  const size_t MD = (size_t)Mrows * DIM;   // 4194304
  const size_t WD = (size_t)DIM * DIM;     // 1048576
  bf16_t* W = (bf16_t*)d_ws;
  bf16_t* x_bf  = W;
  bf16_t* wq_bf = x_bf + MD;               // wq|wk|wv contiguous = [3072][1024]
  bf16_t* wk_bf = wq_bf + WD;
  bf16_t* wv_bf = wk_bf + WD;
  bf16_t* wo_bf = wv_bf + WD;
  bf16_t* q_lin = wo_bf + WD;
  bf16_t* k_lin = q_lin + MD;
  bf16_t* attn_out = k_lin + MD;
  bf16_t* vT    = attn_out + MD;
  float2* tab   = (float2*)(vT + MD);

  k_prep<<<8448, 256, 0, stream>>>(x, wq, wk, wv, wo, x_bf, wq_bf, wk_bf,
                                   wv_bf, wo_bf, tab);

  k_gemm_qkv<<<768, 256, 0, stream>>>(x_bf, wq_bf, bq, bk, bv, q_lin, k_lin,
                                      vT, tab);

  k_attn<<<dim3(16, Bn * NH), 256, 0, stream>>>(q_lin, k_lin, vT, attn_out);

  k_gemm_out<<<256, 256, 0, stream>>>(attn_out, wo_bf, bo, (float*)d_out);
}

// Round 10
// 132.871 us; speedup vs baseline: 1.1959x; 1.1959x over previous
//
#include <hip/hip_runtime.h>
#include <cstdint>
#include <cstddef>

// ---------------------------------------------------------------------------
// MultiHeadAttention (B=2, S=2048, DIM=1024, H=16, HD=64), causal + RoPE.
// R10: un-bundle R9's race. Keep BK=64 swizzled GEMMs (+ explicit vmcnt(0)
// belt-and-braces before the post-stage barrier). Split the post-pass back
// into R4-proven separate launches (k_rope x2, k_trans). attn_out now reuses
// x_bf (dead after QKV GEMM) -> no aliasing with v_lin, no ws growth.
// attn/prep unchanged.
// ---------------------------------------------------------------------------

typedef __bf16 bf16_t;
typedef __bf16 bf16x8 __attribute__((ext_vector_type(8)));
typedef __bf16 bf16x4 __attribute__((ext_vector_type(4)));
typedef float  f32x4  __attribute__((ext_vector_type(4)));

#define DEVFN __device__ __forceinline__

static constexpr int Bn  = 2;
static constexpr int S   = 2048;
static constexpr int DIM = 1024;
static constexpr int NH  = 16;
static constexpr int HD  = 64;
static constexpr int Mrows = Bn * S;        // 4096

DEVFN f32x4 mfma16(bf16x8 a, bf16x8 b, f32x4 c) {
  return __builtin_amdgcn_mfma_f32_16x16x32_bf16(a, b, c, 0, 0, 0);
}

DEVFN void gl_lds16(const bf16_t* g, bf16_t* l) {
  __builtin_amdgcn_global_load_lds(
      (const __attribute__((address_space(1))) unsigned*)g,
      (__attribute__((address_space(3))) unsigned*)l, 16, 0, 0);
}

// ---------------------------------------------------------------------------
// One launch: all fp32->bf16 converts + rope table.
__global__ __launch_bounds__(256) void k_prep(
    const float* __restrict__ x, const float* __restrict__ wq,
    const float* __restrict__ wk, const float* __restrict__ wv,
    const float* __restrict__ wo, bf16_t* __restrict__ xb,
    bf16_t* __restrict__ wqb, bf16_t* __restrict__ wkb,
    bf16_t* __restrict__ wvb, bf16_t* __restrict__ wob,
    float2* __restrict__ tab) {
  const int bid = blockIdx.x;
  if (bid < 8192) {
    const float* src;
    bf16_t* dst;
    size_t base;
    if (bid < 4096) {
      src = x; dst = xb; base = (size_t)bid << 10;
    } else {
      int wsel = (bid - 4096) >> 10;
      src = wsel == 0 ? wq : wsel == 1 ? wk : wsel == 2 ? wv : wo;
      dst = wsel == 0 ? wqb : wsel == 1 ? wkb : wsel == 2 ? wvb : wob;
      base = (size_t)((bid - 4096) & 1023) << 10;
    }
    size_t i = base + (size_t)threadIdx.x * 4;
    float4 v = *(const float4*)(src + i);
    bf16x4 o = { (bf16_t)v.x, (bf16_t)v.y, (bf16_t)v.z, (bf16_t)v.w };
    *(bf16x4*)(dst + i) = o;
  } else {
    int i = (bid - 8192) * 256 + threadIdx.x;  // < S*32
    int s = i >> 5, d = i & 31;
    float th = (float)s * expf((float)d * -0.2878231366f);  // ln(10000)/32
    tab[i] = make_float2(cosf(th), sinf(th));
  }
}

// ---------------------------------------------------------------------------
// in-place rope on [Mrows][DIM] bf16 (R4-proven body).
__global__ __launch_bounds__(256) void k_rope(bf16_t* __restrict__ X,
                                              const float2* __restrict__ tab,
                                              float scale) {
  int i = blockIdx.x * 256 + threadIdx.x;   // chunk of 8 elems
  int row = i >> 7;
  int s = row & (S - 1);
  int dd = (i & 7) << 3;
  int p0 = dd >> 1;
  bf16x8 v = *(bf16x8*)(X + (size_t)i * 8);
  bf16x8 o;
#pragma unroll
  for (int j = 0; j < 4; ++j) {
    float x1 = (float)v[2 * j], x2 = (float)v[2 * j + 1];
    float2 cs = tab[s * 32 + p0 + j];
    o[2 * j]     = (bf16_t)((x1 * cs.x - x2 * cs.y) * scale);
    o[2 * j + 1] = (bf16_t)((x1 * cs.y + x2 * cs.x) * scale);
  }
  *(bf16x8*)(X + (size_t)i * 8) = o;
}

// V [b][s][h][d] -> VT [b*h][d][s] (R4-proven body).
__global__ __launch_bounds__(256) void k_trans(const bf16_t* __restrict__ Vin,
                                               bf16_t* __restrict__ VT) {
  __shared__ __align__(16) bf16_t tile[64][72];
  int s0 = blockIdx.x * 64, bh = blockIdx.y;
  int b = bh >> 4, h = bh & 15;
  int t = threadIdx.x;
#pragma unroll
  for (int it = 0; it < 2; ++it) {
    int sl = (t >> 3) + it * 32, d0 = (t & 7) << 3;
    *(bf16x8*)&tile[sl][d0] =
        *(const bf16x8*)(Vin + (size_t)(b * S + s0 + sl) * DIM + h * HD + d0);
  }
  __syncthreads();
  int d = t >> 2, c0 = (t & 3) * 16;
  bf16_t buf[16];
#pragma unroll
  for (int j = 0; j < 16; ++j) buf[j] = tile[c0 + j][d];
  bf16_t* op = VT + ((size_t)bh * HD + d) * S + s0 + c0;
  *(bf16x8*)op = *(bf16x8*)&buf[0];
  *(bf16x8*)(op + 8) = *(bf16x8*)&buf[8];
}

// ---------------------------------------------------------------------------
// GEMM staging, BK=64 tile [128 rows][64 k] per matrix. Source pre-swizzled
// j=((c&7)^(row&7))*8, LDS dest linear; read back with byte-XOR ((row&7)<<4).
DEVFN void stage64(const bf16_t* __restrict__ A, const bf16_t* __restrict__ Bw,
                   bf16_t* Al, bf16_t* Bl, int m0, int n0, int k0, int t,
                   int w) {
#pragma unroll
  for (int ld = 0; ld < 4; ++ld) {
    int c = t + ld * 256;
    int row = c >> 3;
    int j = ((c & 7) ^ (row & 7)) << 3;
    bf16_t* dstA = Al + (size_t)(w * 64 + ld * 256) * 8;
    bf16_t* dstB = Bl + (size_t)(w * 64 + ld * 256) * 8;
    gl_lds16(A + (size_t)(m0 + row) * DIM + k0 + j, dstA);
    gl_lds16(Bw + (size_t)(n0 + row) * DIM + k0 + j, dstB);
  }
}

// ---------------------------------------------------------------------------
// Fused QKV NT GEMM: M=4096, N=3072 (wq|wk|wv contiguous), K=1024. 128x128
// tile, BK=64 (16 iters). 768 blocks, XCD rectangle swizzle. Plain bias
// epilogue -> q_lin/k_lin/v_lin.
__global__ __launch_bounds__(256) void k_gemm_qkv(
    const bf16_t* __restrict__ A, const bf16_t* __restrict__ Wall,
    const float* __restrict__ c0, const float* __restrict__ c1,
    const float* __restrict__ c2, bf16_t* __restrict__ Oq,
    bf16_t* __restrict__ Ok, bf16_t* __restrict__ Ov_) {
  __shared__ __align__(16) bf16_t Al[128 * 64];
  __shared__ __align__(16) bf16_t Bl[128 * 64];
  const int t = threadIdx.x, w = t >> 6, l = t & 63;
  const int lr = l & 15, lc = l >> 4;
  const int lid = blockIdx.x;
  const int xcd = lid & 7, s = lid >> 3;          // s in [0,96)
  const int my = ((xcd >> 1) << 3) + (s & 7);     // [0,32)
  const int nx = (xcd & 1) * 12 + (s >> 3);       // [0,24)
  const int m0 = my * 128, n0g = nx * 128;
  const int z = n0g >> 10, n0l = n0g & 1023;
  const int wr = w >> 1, wc = w & 1;
  f32x4 acc[4][4] = {};

  for (int k0 = 0; k0 < DIM; k0 += 64) {
    __syncthreads();
    stage64(A, Wall, Al, Bl, m0, n0g, k0, t, w);
    asm volatile("s_waitcnt vmcnt(0)" ::: "memory");  // belt-and-braces drain
    __syncthreads();
    bf16x8 af[2][4], bfr[2][4];
#pragma unroll
    for (int ks = 0; ks < 2; ++ks) {
#pragma unroll
      for (int mi = 0; mi < 4; ++mi) {
        int row = wr * 64 + mi * 16 + lr;
        int off = ((ks * 4 + lc) << 4) ^ ((row & 7) << 4);
        af[ks][mi] = *(const bf16x8*)((const char*)Al + row * 128 + off);
      }
#pragma unroll
      for (int ni = 0; ni < 4; ++ni) {
        int row = wc * 64 + ni * 16 + lr;
        int off = ((ks * 4 + lc) << 4) ^ ((row & 7) << 4);
        bfr[ks][ni] = *(const bf16x8*)((const char*)Bl + row * 128 + off);
      }
    }
    __builtin_amdgcn_s_setprio(1);
#pragma unroll
    for (int ks = 0; ks < 2; ++ks)
#pragma unroll
      for (int mi = 0; mi < 4; ++mi)
#pragma unroll
        for (int ni = 0; ni < 4; ++ni)
          acc[mi][ni] = mfma16(af[ks][mi], bfr[ks][ni], acc[mi][ni]);
    __builtin_amdgcn_s_setprio(0);
  }

  bf16_t* Ov = z == 0 ? Oq : (z == 1 ? Ok : Ov_);
  const float* bias = z == 0 ? c0 : (z == 1 ? c1 : c2);
#pragma unroll
  for (int ni = 0; ni < 4; ++ni) {
    const int col = n0l + wc * 64 + ni * 16 + lr;
    const float bv = bias[col];
#pragma unroll
    for (int mi = 0; mi < 4; ++mi)
#pragma unroll
      for (int r = 0; r < 4; ++r) {
        int row = m0 + wr * 64 + mi * 16 + lc * 4 + r;
        Ov[(size_t)row * DIM + col] = (bf16_t)(acc[mi][ni][r] + bv);
      }
  }
}

// ---------------------------------------------------------------------------
// Out projection: M=4096, N=1024, K=1024. 256 blocks, same BK=64 loop.
__global__ __launch_bounds__(256) void k_gemm_out(
    const bf16_t* __restrict__ A, const bf16_t* __restrict__ Bw,
    const float* __restrict__ bias, float* __restrict__ Ov) {
  __shared__ __align__(16) bf16_t Al[128 * 64];
  __shared__ __align__(16) bf16_t Bl[128 * 64];
  const int t = threadIdx.x, w = t >> 6, l = t & 63;
  const int lr = l & 15, lc = l >> 4;
  const int lid = blockIdx.x;
  const int xcd = lid & 7, s = lid >> 3;          // s in [0,32)
  const int my = ((xcd >> 1) << 3) + (s & 7);     // [0,32)
  const int nx = (xcd & 1) * 4 + (s >> 3);        // [0,8)
  const int m0 = my * 128, n0 = nx * 128;
  const int wr = w >> 1, wc = w & 1;
  f32x4 acc[4][4] = {};

  for (int k0 = 0; k0 < DIM; k0 += 64) {
    __syncthreads();
    stage64(A, Bw, Al, Bl, m0, n0, k0, t, w);
    asm volatile("s_waitcnt vmcnt(0)" ::: "memory");  // belt-and-braces drain
    __syncthreads();
    bf16x8 af[2][4], bfr[2][4];
#pragma unroll
    for (int ks = 0; ks < 2; ++ks) {
#pragma unroll
      for (int mi = 0; mi < 4; ++mi) {
        int row = wr * 64 + mi * 16 + lr;
        int off = ((ks * 4 + lc) << 4) ^ ((row & 7) << 4);
        af[ks][mi] = *(const bf16x8*)((const char*)Al + row * 128 + off);
      }
#pragma unroll
      for (int ni = 0; ni < 4; ++ni) {
        int row = wc * 64 + ni * 16 + lr;
        int off = ((ks * 4 + lc) << 4) ^ ((row & 7) << 4);
        bfr[ks][ni] = *(const bf16x8*)((const char*)Bl + row * 128 + off);
      }
    }
    __builtin_amdgcn_s_setprio(1);
#pragma unroll
    for (int ks = 0; ks < 2; ++ks)
#pragma unroll
      for (int mi = 0; mi < 4; ++mi)
#pragma unroll
        for (int ni = 0; ni < 4; ++ni)
          acc[mi][ni] = mfma16(af[ks][mi], bfr[ks][ni], acc[mi][ni]);
    __builtin_amdgcn_s_setprio(0);
  }

#pragma unroll
  for (int ni = 0; ni < 4; ++ni) {
    int col = n0 + wc * 64 + ni * 16 + lr;
    float bv = bias[col];
#pragma unroll
    for (int mi = 0; mi < 4; ++mi)
#pragma unroll
      for (int r = 0; r < 4; ++r) {
        int row = m0 + wr * 64 + mi * 16 + lc * 4 + r;
        Ov[(size_t)row * DIM + col] = acc[mi][ni][r] + bv;
      }
  }
}

// ---------------------------------------------------------------------------
// Causal flash attention (unchanged — post-timing-validated in R6/R7/R8).
DEVFN void stage_kv(const bf16_t* __restrict__ Kc,
                    const bf16_t* __restrict__ VT, bf16_t* Kb, bf16_t* Vb,
                    int b, int bh, int h, int k0, int tid, int w) {
#pragma unroll
  for (int ld = 0; ld < 2; ++ld) {
    int c = tid + ld * 256;
    int row = c >> 3;
    int j = ((c & 7) ^ (row & 7)) << 3;  // pre-swizzled source chunk
    bf16_t* dstK = Kb + (size_t)(w * 64 + ld * 256) * 8;
    bf16_t* dstV = Vb + (size_t)(w * 64 + ld * 256) * 8;
    gl_lds16(Kc + (size_t)(b * S + k0 + row) * DIM + h * HD + j, dstK);
    gl_lds16(VT + ((size_t)bh * HD + row) * S + k0 + j, dstV);
  }
}

__global__ __launch_bounds__(256) void k_attn(const bf16_t* __restrict__ Q,
                                              const bf16_t* __restrict__ Kc,
                                              const bf16_t* __restrict__ VT,
                                              bf16_t* __restrict__ O) {
  __shared__ __align__(16) bf16_t Kl[2][64 * 64];
  __shared__ __align__(16) bf16_t Vl[3][64 * 64];
  __shared__ __align__(16) bf16_t Pl[4][16 * 64];
  const int tid = threadIdx.x, w = tid >> 6, l = tid & 63;
  const int lr = l & 15, lc = l >> 4;
  const int lid = blockIdx.x + (blockIdx.y << 4);
  const int xcd = lid & 7, slot = lid >> 3;
  const int bh = xcd * 4 + (slot >> 4);
  const int a = slot & 15;
  const int b = bh >> 4, h = bh & 15;
  char* Pw = (char*)&Pl[w][0];

#pragma unroll 1
  for (int pi = 0; pi < 2; ++pi) {
    const int tile = (pi == 0) ? a : 31 - a;
    const int q0 = tile * 64;
    const int nt = tile + 1;

    bf16x8 qf[2];
    {
      const bf16_t* qp =
          Q + (size_t)(b * S + q0 + w * 16 + lr) * DIM + h * HD + lc * 8;
      qf[0] = *(const bf16x8*)qp;
      qf[1] = *(const bf16x8*)(qp + 32);
    }
    f32x4 o[4] = {};
    f32x4 sA[4], sB[4];
    float m_run = -INFINITY;
    float rowsum = 0.f;

    auto qkt = [&](f32x4(&sd)[4], const bf16_t* Kb) {
#pragma unroll
      for (int ni = 0; ni < 4; ++ni) sd[ni] = f32x4{0.f, 0.f, 0.f, 0.f};
      __builtin_amdgcn_s_setprio(1);
#pragma unroll
      for (int ks = 0; ks < 2; ++ks)
#pragma unroll
        for (int ni = 0; ni < 4; ++ni) {
          int row = ni * 16 + lr;
          int off = (ks * 64 + lc * 16) ^ ((row & 7) << 4);
          bf16x8 kf = *(const bf16x8*)((const char*)Kb + row * 128 + off);
          sd[ni] = mfma16(kf, qf[ks], sd[ni]);
        }
      __builtin_amdgcn_s_setprio(0);
    };

    stage_kv(Kc, VT, &Kl[0][0], &Vl[0][0], b, bh, h, 0, tid, w);
    if (nt > 1) {
      stage_kv(Kc, VT, &Kl[1][0], &Vl[1][0], b, bh, h, 64, tid, w);
      asm volatile("s_waitcnt vmcnt(4)" ::: "memory");
    } else {
      asm volatile("s_waitcnt vmcnt(0)" ::: "memory");
    }
    __builtin_amdgcn_s_barrier();
    __builtin_amdgcn_sched_barrier(0);
    qkt(sA, &Kl[0][0]);
    __builtin_amdgcn_s_barrier();

    auto body = [&](f32x4(&scur)[4], f32x4(&snxt)[4], int t) {
      if (t + 2 < nt)
        stage_kv(Kc, VT, &Kl[(t + 2) & 1][0], &Vl[(t + 2) % 3][0], b, bh, h,
                 (t + 2) * 64, tid, w);
      if (t + 1 < nt) {
        if (t + 2 < nt)
          asm volatile("s_waitcnt vmcnt(4)" ::: "memory");
        else
          asm volatile("s_waitcnt vmcnt(0)" ::: "memory");
        __builtin_amdgcn_s_barrier();
        __builtin_amdgcn_sched_barrier(0);
        qkt(snxt, &Kl[(t + 1) & 1][0]);
      }

      if (t == nt - 1) {
        const int qloc = w * 16 + lr;
#pragma unroll
        for (int ni = 0; ni < 4; ++ni)
#pragma unroll
          for (int r = 0; r < 4; ++r)
            if (ni * 16 + lc * 4 + r > qloc) scur[ni][r] = -INFINITY;
      }

      float pm = scur[0][0];
#pragma unroll
      for (int ni = 0; ni < 4; ++ni)
#pragma unroll
        for (int r = 0; r < 4; ++r) pm = fmaxf(pm, scur[ni][r]);
      pm = fmaxf(pm, __shfl_xor(pm, 16));
      pm = fmaxf(pm, __shfl_xor(pm, 32));

      if (__ballot(pm > m_run + 8.f)) {
        float mn = fmaxf(m_run, pm);
        float alpha = __expf(m_run - mn);
        m_run = mn;
        rowsum *= alpha;
#pragma unroll
        for (int r = 0; r < 4; ++r) {
          float aq = __shfl(alpha, lc * 4 + r);
#pragma unroll
          for (int ni = 0; ni < 4; ++ni) o[ni][r] *= aq;
        }
      }

      float rs = 0.f;
#pragma unroll
      for (int ni = 0; ni < 4; ++ni) {
        float p0 = __expf(scur[ni][0] - m_run);
        float p1 = __expf(scur[ni][1] - m_run);
        float p2 = __expf(scur[ni][2] - m_run);
        float p3 = __expf(scur[ni][3] - m_run);
        rs += (p0 + p1) + (p2 + p3);
        bf16x4 pb = { (bf16_t)p0, (bf16_t)p1, (bf16_t)p2, (bf16_t)p3 };
        *(bf16x4*)(Pw + (lr * 128 + ((ni * 32 + lc * 8) ^ ((lr & 7) << 4)))) =
            pb;
      }
      rs += __shfl_xor(rs, 16);
      rs += __shfl_xor(rs, 32);
      rowsum += rs;

      const bf16_t* Vb = &Vl[t % 3][0];
      __builtin_amdgcn_s_setprio(1);
#pragma unroll
      for (int ks = 0; ks < 2; ++ks) {
        int off = ks * 64 + lc * 16;
        bf16x8 pa = *(const bf16x8*)(Pw + lr * 128 + (off ^ ((lr & 7) << 4)));
#pragma unroll
        for (int ni = 0; ni < 4; ++ni) {
          int vrow = ni * 16 + lr;
          bf16x8 vb = *(const bf16x8*)((const char*)Vb + vrow * 128 +
                                       (off ^ ((vrow & 7) << 4)));
          o[ni] = mfma16(pa, vb, o[ni]);
        }
      }
      __builtin_amdgcn_s_setprio(0);

      __builtin_amdgcn_s_barrier();
    };

#pragma unroll 1
    for (int t = 0; t < nt; ++t) {
      if (t & 1)
        body(sB, sA, t);
      else
        body(sA, sB, t);
    }

    float inv[4];
#pragma unroll
    for (int r = 0; r < 4; ++r) inv[r] = 1.0f / __shfl(rowsum, lc * 4 + r);
#pragma unroll
    for (int ni = 0; ni < 4; ++ni)
#pragma unroll
      for (int r = 0; r < 4; ++r) {
        int qr = q0 + w * 16 + lc * 4 + r;
        float v = o[ni][r] * inv[r];
        O[(size_t)(b * S + qr) * DIM + h * HD + ni * 16 + lr] = (bf16_t)v;
      }
  }
}

// ---------------------------------------------------------------------------
extern "C" void kernel_launch(void* const* d_in, const int* in_sizes, int n_in,
                              void* d_out, int out_size, void* d_ws,
                              size_t ws_size, hipStream_t stream) {
  const float* x  = (const float*)d_in[0];
  const float* wq = (const float*)d_in[1];
  const float* bq = (const float*)d_in[2];
  const float* wk = (const float*)d_in[3];
  const float* bk = (const float*)d_in[4];
  const float* wv = (const float*)d_in[5];
  const float* bv = (const float*)d_in[6];
  const float* wo = (const float*)d_in[7];
  const float* bo = (const float*)d_in[8];

  const size_t MD = (size_t)Mrows * DIM;   // 4194304
  const size_t WD = (size_t)DIM * DIM;     // 1048576
  bf16_t* W = (bf16_t*)d_ws;
  bf16_t* x_bf  = W;
  bf16_t* wq_bf = x_bf + MD;               // wq|wk|wv contiguous = [3072][1024]
  bf16_t* wk_bf = wq_bf + WD;
  bf16_t* wv_bf = wk_bf + WD;
  bf16_t* wo_bf = wv_bf + WD;
  bf16_t* q_lin = wo_bf + WD;
  bf16_t* k_lin = q_lin + MD;
  bf16_t* v_lin = k_lin + MD;
  bf16_t* vT    = v_lin + MD;
  float2* tab   = (float2*)(vT + MD);
  bf16_t* attn_out = x_bf;  // x_bf dead after k_gemm_qkv; rewritten by k_prep
                            // every call -> no cross-call state dependency

  k_prep<<<8448, 256, 0, stream>>>(x, wq, wk, wv, wo, x_bf, wq_bf, wk_bf,
                                   wv_bf, wo_bf, tab);

  k_gemm_qkv<<<768, 256, 0, stream>>>(x_bf, wq_bf, bq, bk, bv, q_lin, k_lin,
                                      v_lin);

  k_rope<<<2048, 256, 0, stream>>>(q_lin, tab, 0.125f);
  k_rope<<<2048, 256, 0, stream>>>(k_lin, tab, 1.0f);
  k_trans<<<dim3(S / 64, Bn * NH), 256, 0, stream>>>(v_lin, vT);

  k_attn<<<dim3(16, Bn * NH), 256, 0, stream>>>(q_lin, k_lin, vT, attn_out);

  k_gemm_out<<<256, 256, 0, stream>>>(attn_out, wo_bf, bo, (float*)d_out);
}